// Round 1
// baseline (149.704 us; speedup 1.0000x reference)
//
#include <hip/hip_runtime.h>
#include <math.h>

#define S_LEN 512
#define BATCH 16
#define DIN   512
#define DF    512
#define NMIX  10
#define NCHAR 1024
#define DCTX  256
#define M_ROWS (S_LEN*BATCH)   // 8192

// d_out layout (tuple flattened in return order)
#define OFF_CTXOUT 0
#define OFF_ATTN   (S_LEN*BATCH*DCTX)
#define OFF_MEANS  (OFF_ATTN + S_LEN*BATCH*NCHAR)
#define OFF_VARS   (OFF_MEANS + S_LEN*BATCH*NMIX)
#define OFF_WTS    (OFF_VARS  + S_LEN*BATCH*NMIX)

// scratch layout in d_ws (byte offsets)
#define WS_HH    0            // f16  8 MB   (8192x512)
#define WS_W2T   (8u<<20)     // f32  64 KB  (32x512 padded, [j][k])
#define WS_DM    (9u<<20)     // f32  320 KB delta-means, chain-major [b][k][s]

typedef float    f32x16 __attribute__((ext_vector_type(16)));
typedef float    f32x4v __attribute__((ext_vector_type(4)));
typedef _Float16 f16x8  __attribute__((ext_vector_type(8)));

__device__ __forceinline__ unsigned short f2h(float x) {
    union { _Float16 h; unsigned short u; } cv;
    cv.h = (_Float16)x;
    return cv.u;
}
__device__ __forceinline__ ushort4 cvt4(float4 v) {
    ushort4 o; o.x = f2h(v.x); o.y = f2h(v.y); o.z = f2h(v.z); o.w = f2h(v.w);
    return o;
}
__device__ __forceinline__ void nt_store4(float* p, float a, float b, float c, float d) {
    f32x4v v; v.x = a; v.y = b; v.z = c; v.w = d;
    __builtin_nontemporal_store(v, (f32x4v*)p);
}

// LDS tile convention (all MFMA tiles): row stride 64 f16 (128 B), XOR swizzle
// of the 8-f16 granule index by (row&7): addr = row*64 + (col8 ^ ((row&7)<<3)) + sub
// (m214-verified conflict-free pattern for ds_read_b128 at 128 B stride).

// ---------------------------------------------------------------------------
// Kernel 1: fused GEMM1 (X f32 -> leakyrelu(X@W1+b1) f16), staging converts
// f32->f16 on the fly; B transposed during LDS store.  Blocks >= 512 build
// W2T (f32 [j][k], 32x512 padded) for gemm2.
// ---------------------------------------------------------------------------
__global__ __launch_bounds__(256) void gemm1_kernel(
    const float* __restrict__ X, const float* __restrict__ W1,
    const float* __restrict__ b1, unsigned short* __restrict__ Hh,
    const float* __restrict__ W2, float* __restrict__ W2T)
{
    const int tid = threadIdx.x;
    if (blockIdx.x >= 512) {
        const int base = (blockIdx.x - 512) * 4096 + tid;
        #pragma unroll
        for (int i = 0; i < 16; i++) {
            const int idx = base + i*256;          // 0..16383 over 4 blocks
            const int j = idx >> 9, k = idx & 511;
            W2T[idx] = (j < 30) ? W2[k*30 + j] : 0.f;
        }
        return;
    }
    __shared__ __align__(16) unsigned short As[64*64];
    __shared__ __align__(16) unsigned short Bs[128*64];
    const int row0 = (blockIdx.x >> 2) * 64;
    const int n0   = (blockIdx.x & 3)  * 128;
    const int lane = tid & 63, w = tid >> 6;
    const int wr = (w >> 1) * 32, wc = (w & 1) * 64;
    const int m  = lane & 31,  g  = lane >> 5;
    // A staging: thread covers (row sa, cols ka..ka+15)
    const int sa = tid >> 2, ka = (tid & 3) * 16;
    // B staging: thread covers (k-row kb, cols nq..nq+31), written transposed
    const int kb = tid & 63, nq = (tid >> 6) * 32;

    f32x16 acc0 = {}, acc1 = {};
    const float* aptr = X + (size_t)(row0 + sa)*DIN + ka;
    const int sza = (sa & 7) << 3;
    const int szm = (m  & 7) << 3;

    for (int kt = 0; kt < DIN; kt += 64) {
        float4 a0 = *(const float4*)(aptr + kt + 0);
        float4 a1 = *(const float4*)(aptr + kt + 4);
        float4 a2 = *(const float4*)(aptr + kt + 8);
        float4 a3 = *(const float4*)(aptr + kt + 12);
        const float* bp = W1 + (size_t)(kt + kb)*DF + n0 + nq;
        float4 bv[8];
        #pragma unroll
        for (int u = 0; u < 8; u++) bv[u] = *(const float4*)(bp + u*4);
        __syncthreads();
        {
            union { ushort4 h[4]; uint4 q[2]; } ta;
            ta.h[0] = cvt4(a0); ta.h[1] = cvt4(a1);
            ta.h[2] = cvt4(a2); ta.h[3] = cvt4(a3);
            *(uint4*)(As + sa*64 + ( ka      ^ sza)) = ta.q[0];
            *(uint4*)(As + sa*64 + ((ka + 8) ^ sza)) = ta.q[1];
        }
        {
            const int cb = (kb & ~7), cs = (kb & 7);
            #pragma unroll
            for (int u = 0; u < 8; u++) {
                ushort4 h = cvt4(bv[u]);
                const int n = nq + u*4;
                Bs[(n+0)*64 + (cb ^ (((n+0)&7)<<3)) + cs] = h.x;
                Bs[(n+1)*64 + (cb ^ (((n+1)&7)<<3)) + cs] = h.y;
                Bs[(n+2)*64 + (cb ^ (((n+2)&7)<<3)) + cs] = h.z;
                Bs[(n+3)*64 + (cb ^ (((n+3)&7)<<3)) + cs] = h.w;
            }
        }
        __syncthreads();
        #pragma unroll
        for (int ks = 0; ks < 64; ks += 16) {
            const int ac = ks + g*8;
            f16x8 af  = *(const f16x8*)(As + (wr+m)*64      + (ac ^ szm));
            f16x8 bf0 = *(const f16x8*)(Bs + (wc+m)*64      + (ac ^ szm));
            f16x8 bf1 = *(const f16x8*)(Bs + (wc+32+m)*64   + (ac ^ szm));
            acc0 = __builtin_amdgcn_mfma_f32_32x32x16_f16(af, bf0, acc0, 0, 0, 0);
            acc1 = __builtin_amdgcn_mfma_f32_32x32x16_f16(af, bf1, acc1, 0, 0, 0);
        }
    }
    const int nc0 = n0 + wc + m;
    const float bb0 = b1[nc0], bb1 = b1[nc0 + 32];
    #pragma unroll
    for (int r = 0; r < 16; r++) {
        const int rowloc = (r & 3) + 8*(r >> 2) + 4*g;
        const int row = row0 + wr + rowloc;
        float v0 = acc0[r] + bb0;
        float v1 = acc1[r] + bb1;
        v0 = v0 > 0.f ? v0 : 0.01f * v0;
        v1 = v1 > 0.f ? v1 : 0.01f * v1;
        Hh[(size_t)row*DF + nc0]      = f2h(v0);
        Hh[(size_t)row*DF + nc0 + 32] = f2h(v1);
    }
}

// ---------------------------------------------------------------------------
// Kernel 2: GEMM2 (8192x30, K=512); LDS-staged H, broadcast W2T reads.
// delta-means now written chain-major to scratch for the fused scan.
// ---------------------------------------------------------------------------
__global__ __launch_bounds__(256) void gemm2_kernel(
    const unsigned short* __restrict__ Hh, const float* __restrict__ W2T,
    const float* __restrict__ b2,
    float* __restrict__ dm_ws, float* __restrict__ dvars, float* __restrict__ dwts)
{
    __shared__ __align__(16) unsigned short Hs[32*520];
    const int tid = threadIdx.x;
    const int r0  = blockIdx.x * 32;
    {
        const uint4* src = (const uint4*)(Hh + (size_t)r0*DF);
        #pragma unroll
        for (int i = 0; i < 8; i++) {
            int u   = tid + i*256;
            int row = u >> 6;
            int col = (u & 63) * 8;
            *(uint4*)(Hs + row*520 + col) = src[u];
        }
    }
    __syncthreads();

    const int r  = tid & 31;
    const int j0 = tid >> 5;
    const unsigned short* hrow = Hs + r*520;
    float acc[4] = {0.f, 0.f, 0.f, 0.f};

    for (int k0 = 0; k0 < DF; k0 += 8) {
        union { uint4 u; _Float16 h[8]; } hv;
        hv.u = *(const uint4*)(hrow + k0);
        float wv[4][8];
        #pragma unroll
        for (int q = 0; q < 4; q++) {
            *(float4*)(wv[q])     = *(const float4*)(W2T + (size_t)(j0 + q*8)*DF + k0);
            *(float4*)(wv[q] + 4) = *(const float4*)(W2T + (size_t)(j0 + q*8)*DF + k0 + 4);
        }
        #pragma unroll
        for (int i = 0; i < 8; i++) {
            float hf = (float)hv.h[i];
            acc[0] = fmaf(hf, wv[0][i], acc[0]);
            acc[1] = fmaf(hf, wv[1][i], acc[1]);
            acc[2] = fmaf(hf, wv[2][i], acc[2]);
            acc[3] = fmaf(hf, wv[3][i], acc[3]);
        }
    }
    const int row = r0 + r;
    #pragma unroll
    for (int q = 0; q < 4; q++) {
        const int j = j0 + q*8;
        if (j >= 30) continue;
        float dot = acc[q] + b2[j];
        float sp  = fmaxf(dot, 0.f) + log1pf(__expf(-fabsf(dot)));
        if (j < 10) {
            // chain-major: [b][k][s] for coalesced wave-scan in the fused kernel
            const int bb = row & (BATCH-1), s = row >> 4;
            dm_ws[((size_t)bb*NMIX + j)*S_LEN + s] = sp * (1.f/25.f);
        }
        else if (j < 20)  dvars[row*NMIX + (j-10)] = fminf(fmaxf(sp, 0.01f), 100.f);
        else              dwts [row*NMIX + (j-20)] = sp;
    }
}

// ---------------------------------------------------------------------------
// Kernel 3: fused scan + attention weights + attended contexts.
// Grid: (batch=16) x (16 s-tiles of 32 rows) = 256 blocks, 512 threads.
// Per block: shuffle-scan its batch's delta-mean chains up to its rows,
// local reach bound (tighter than global), then per-64-char chunk:
// attn f32 out + f16 LDS tile + ctx staged (f32->f16, transposed) + MFMA.
// ---------------------------------------------------------------------------
__global__ __launch_bounds__(512) void fused_kernel(
    const float* __restrict__ dm_ws, const float* __restrict__ init_means,
    const float* __restrict__ vars_g, const float* __restrict__ wts_g,
    const float* __restrict__ ctx,
    float* __restrict__ means_out, float* __restrict__ attn_out,
    float* __restrict__ ctxout)
{
    __shared__ float mlds[320];
    __shared__ float vlds[320];
    __shared__ float wlds[320];
    __shared__ float redbuf[8];
    __shared__ __align__(16) unsigned short As[32*64];
    __shared__ __align__(16) unsigned short Bs[256*64];

    const int bid = blockIdx.x;
    const int b   = bid >> 4;          // batch
    const int s0  = (bid & 15) * 32;   // first row of tile
    const int tid = threadIdx.x;
    const int lane = tid & 63, w = tid >> 6;   // 8 waves
    const int m = lane & 31, g = lane >> 5;

    // ---- inclusive scan of delta-means (chains this block needs) ----
    const int send = s0 + 32;
    for (int k = w; k < NMIX; k += 8) {
        float carry = init_means[b*NMIX + k];
        const float* chain = dm_ws + ((size_t)b*NMIX + k)*S_LEN;
        for (int sseg = 0; sseg < send; sseg += 64) {
            const int s = sseg + lane;
            float v = (s < send) ? chain[s] : 0.f;
            #pragma unroll
            for (int d = 1; d < 64; d <<= 1) {
                float t = __shfl_up(v, d, 64);
                if (lane >= d) v += t;
            }
            const float x = v + carry;
            carry = __shfl(x, 63, 64);
            if (s >= s0 && s < send) mlds[(s - s0)*NMIX + k] = x;
        }
    }
    if (tid < 320) {
        const int s = tid / NMIX, k = tid - s*NMIX;
        const int row = (s0 + s)*BATCH + b;
        vlds[tid] = vars_g[row*NMIX + k];
        wlds[tid] = wts_g [row*NMIX + k];
    }
    __syncthreads();

    // ---- means output + local reach bound ----
    float reach = 0.f;
    if (tid < 320) {
        const int s = tid / NMIX, k = tid - s*NMIX;
        means_out[((s0 + s)*BATCH + b)*NMIX + k] = mlds[tid];
        reach = mlds[tid] + 4.8f * rsqrtf(vlds[tid]);
    }
    #pragma unroll
    for (int d = 32; d >= 1; d >>= 1) reach = fmaxf(reach, __shfl_xor(reach, d, 64));
    if (lane == 0) redbuf[w] = reach;
    __syncthreads();
    float rmax = redbuf[0];
    #pragma unroll
    for (int i = 1; i < 8; i++) rmax = fmaxf(rmax, redbuf[i]);
    const int kmax = min(NCHAR, (((int)rmax) + 64) & ~63);

    // ---- per-thread row params (row r fixed across chunks) ----
    const int r  = tid >> 4;       // 0..31
    const int ti = tid & 15;       // 0..15 -> 4 chars each
    float mr[NMIX], vr[NMIX], wr_[NMIX];
    #pragma unroll
    for (int k = 0; k < NMIX; k++) {
        mr[k] = mlds[r*NMIX + k];
        vr[k] = vlds[r*NMIX + k];
        wr_[k] = wlds[r*NMIX + k];
    }
    const size_t arow = (size_t)((s0 + r)*BATCH + b) * NCHAR;

    // ctx staging ids: thread covers (char-row tb, d = dq*32..+31)
    const int tb = tid & 63, dq = tid >> 6;
    const float* cbase = ctx + (size_t)b*DCTX + dq*32;
    const int szm = (m & 7) << 3;

    f32x16 acc = {};
    for (int kt = 0; kt < kmax; kt += 64) {
        // attention weights for t = kt + ti*4 .. +3 of row r
        float o[4];
        #pragma unroll
        for (int i = 0; i < 4; i++) {
            const float t = (float)(kt + ti*4 + i);
            float sum = 0.f;
            #pragma unroll
            for (int k = 0; k < NMIX; k++) {
                float d = t - mr[k];
                sum += wr_[k] * __expf(-d*d*vr[k]);
            }
            o[i] = sum;
        }
        // issue ctx loads before the barrier (latency overlap)
        float4 cf[8];
        #pragma unroll
        for (int u = 0; u < 8; u++)
            cf[u] = *(const float4*)(cbase + (size_t)(kt + tb)*(BATCH*DCTX) + u*4);
        __syncthreads();   // previous chunk's MFMA reads done
        nt_store4(attn_out + arow + kt + ti*4, o[0], o[1], o[2], o[3]);
        {
            ushort4 h; h.x = f2h(o[0]); h.y = f2h(o[1]); h.z = f2h(o[2]); h.w = f2h(o[3]);
            const int c = ti*4;
            *(ushort4*)(As + r*64 + ((c & ~7) ^ ((r&7)<<3)) + (c & 7)) = h;
        }
        {
            const int cb = (tb & ~7), cs = (tb & 7);
            #pragma unroll
            for (int u = 0; u < 8; u++) {
                ushort4 h = cvt4(cf[u]);
                const int n = dq*32 + u*4;
                Bs[(n+0)*64 + (cb ^ (((n+0)&7)<<3)) + cs] = h.x;
                Bs[(n+1)*64 + (cb ^ (((n+1)&7)<<3)) + cs] = h.y;
                Bs[(n+2)*64 + (cb ^ (((n+2)&7)<<3)) + cs] = h.z;
                Bs[(n+3)*64 + (cb ^ (((n+3)&7)<<3)) + cs] = h.w;
            }
        }
        __syncthreads();
        #pragma unroll
        for (int ks = 0; ks < 64; ks += 16) {
            const int ac = ks + g*8;
            f16x8 af = *(const f16x8*)(As + m*64 + (ac ^ szm));
            const int brow = w*32 + m;
            f16x8 bf = *(const f16x8*)(Bs + brow*64 + (ac ^ ((brow&7)<<3)));
            acc = __builtin_amdgcn_mfma_f32_32x32x16_f16(af, bf, acc, 0, 0, 0);
        }
    }
    // zero tail of attention output
    for (int t = kmax + ti*4; t < NCHAR; t += 64)
        nt_store4(attn_out + arow + t, 0.f, 0.f, 0.f, 0.f);

    // attended-context epilogue: wave w owns d = w*32 + m, all 32 rows
    #pragma unroll
    for (int rr = 0; rr < 16; rr++) {
        const int rowloc = (rr & 3) + 8*(rr >> 2) + 4*g;
        const int s = s0 + rowloc;
        __builtin_nontemporal_store(acc[rr],
            ctxout + ((size_t)s*BATCH + b)*DCTX + w*32 + m);
    }
}

// ---------------------------------------------------------------------------
extern "C" void kernel_launch(void* const* d_in, const int* in_sizes, int n_in,
                              void* d_out, int out_size, void* d_ws, size_t ws_size,
                              hipStream_t stream)
{
    const float* X     = (const float*)d_in[0];
    const float* ctx   = (const float*)d_in[1];
    const float* initm = (const float*)d_in[2];
    const float* W1    = (const float*)d_in[3];
    const float* b1    = (const float*)d_in[4];
    const float* W2    = (const float*)d_in[5];
    const float* b2    = (const float*)d_in[6];

    float* out      = (float*)d_out;
    float* out_ctx  = out + OFF_CTXOUT;
    float* out_attn = out + OFF_ATTN;
    float* out_mean = out + OFF_MEANS;
    float* out_var  = out + OFF_VARS;
    float* out_wts  = out + OFF_WTS;

    char* ws = (char*)d_ws;
    unsigned short* Hh   = (unsigned short*)(ws + WS_HH);
    float*          W2T  = (float*)         (ws + WS_W2T);
    float*          dmws = (float*)         (ws + WS_DM);

    gemm1_kernel<<<512 + 4, 256, 0, stream>>>(X, W1, b1, Hh, W2, W2T);
    gemm2_kernel<<<M_ROWS/32, 256, 0, stream>>>(Hh, W2T, b2, dmws, out_var, out_wts);
    fused_kernel<<<BATCH*16, 512, 0, stream>>>(dmws, initm, out_var, out_wts, ctx,
                                               out_mean, out_attn, out_ctx);
}